// Round 14
// baseline (232.692 us; speedup 1.0000x reference)
//
#include <hip/hip_runtime.h>
#include <cstdint>
#include <cstddef>

// fp16 internal pipeline. Verified absmax 9.77e-4 (r4-r13), race-stable with
// explicit vmcnt drains around DMA staging (r7+).
// r14: restore r12 exactly — the session-best verified build (225.9 us).
// r13's 128x64 gemm_out retile regressed (~-5 us: halved arithmetic
// intensity, A-traffic doubled). The glue-level config space is exhausted:
// fused gemm_out lost 3x (r8/r10/r11), retile lost (r13); only the prep
// merge won (r12, +5.5 us). Further gains require an attn sync-restructure
// (high risk given the r2/r3 race history).
typedef _Float16 f16x8 __attribute__((ext_vector_type(8)));
typedef __fp16 fp16x2 __attribute__((ext_vector_type(2)));   // builtin cvt_pkrtz return type
typedef float f32x4 __attribute__((ext_vector_type(4)));
typedef float f32x16 __attribute__((ext_vector_type(16)));
typedef unsigned short u16;
typedef unsigned int u32;

static constexpr int Bn = 2;       // batch
static constexpr int L  = 2048;    // sequence
static constexpr int Dm = 1024;    // model dim
static constexpr int H  = 16;      // heads
static constexpr int DH = 64;      // head dim
static constexpr int M  = Bn * L;  // 4096 rows
static constexpr size_t PER = (size_t)Bn * H * L * DH;   // 4M elems
static constexpr int NQ = Bn * H * L;                    // 65536 q rows

static constexpr int CIN_BLK = (M * Dm) / 8 / 256;       // 2048 blocks per tensor
static constexpr int CWT_BLK = (Dm / 64) * (Dm / 64) * 4; // 1024 weight blocks

#define SC 0.18033688f   /* 0.125 * log2(e): folded into Q so QK^T is in exp2 domain */

// RNE fp32 -> fp16 (v_cvt_f16_f32, default round mode = RNE)
__device__ __forceinline__ u16 f2h(float f) {
    _Float16 h = (_Float16)f;
    u16 r; __builtin_memcpy(&r, &h, 2); return r;
}
// RNE pair -> packed u32
__device__ __forceinline__ u32 pk_f16(float a, float b) {
    return (u32)f2h(a) | ((u32)f2h(b) << 16);
}
// RTZ packed pair (single v_cvt_pk_f16_f32). Used ONLY for P, where the
// uniform downward bias cancels in the self-consistent row-sum normalization.
__device__ __forceinline__ u32 pk_rtz(float a, float b) {
#if __has_builtin(__builtin_amdgcn_cvt_pkrtz)
    fp16x2 t = __builtin_amdgcn_cvt_pkrtz(a, b);
    u32 r; __builtin_memcpy(&r, &t, 4); return r;
#else
    return pk_f16(a, b);
#endif
}

// async global->LDS, 16B per lane; LDS dest = wave-uniform base + lane*16
__device__ __forceinline__ void gl2lds16(const void* g, void* l) {
    __builtin_amdgcn_global_load_lds(
        (const __attribute__((address_space(1))) u32*)(uintptr_t)g,
        (__attribute__((address_space(3))) u32*)(uintptr_t)l, 16, 0, 0);
}

// explicit DMA drain before barriers (r7: closes the async-DMA hazard, costs ~0)
__device__ __forceinline__ void drain_vm() {
    asm volatile("s_waitcnt vmcnt(0)" ::: "memory");
}

// ---------------------------------------------------------------------------
// prep: merged convert_in + convert_wt (one dispatch, role by blockIdx.x).
//  - blocks [0, 3*CIN_BLK): fp32->fp16 flat copy of q,k,v
//  - blocks [3*CIN_BLK, +CWT_BLK): fp32 W [K][N] -> fp16 W^T [N][K]
// ---------------------------------------------------------------------------
__global__ __launch_bounds__(256) void prep(
    const float* __restrict__ q, const float* __restrict__ k, const float* __restrict__ v,
    const float* __restrict__ Wq, const float* __restrict__ Wk,
    const float* __restrict__ Wv, const float* __restrict__ Wo,
    u16* __restrict__ dstA, u16* __restrict__ dstW)
{
    __shared__ u16 Ts[64][72];
    const int wid = blockIdx.x;
    const int tid = threadIdx.x;

    if (wid < 3 * CIN_BLK) {
        const int y = wid >> 11;               // tensor select (CIN_BLK = 2048 = 1<<11)
        const float* src = (y == 0) ? q : (y == 1) ? k : v;
        u16* d = dstA + (size_t)y * M * Dm;
        const size_t t = (size_t)(wid & (CIN_BLK - 1)) * 256 + tid;
        const float4* s4 = reinterpret_cast<const float4*>(src) + t * 2;
        float4 f0 = s4[0], f1 = s4[1];
        u32 o[4] = { pk_f16(f0.x, f0.y), pk_f16(f0.z, f0.w),
                     pk_f16(f1.x, f1.y), pk_f16(f1.z, f1.w) };
        reinterpret_cast<uint4*>(d)[t] = *reinterpret_cast<uint4*>(o);
        return;
    }

    const int w = wid - 3 * CIN_BLK;           // 0..1023
    const int z = w >> 8;                      // weight select 0..3
    const int n0 = ((w >> 4) & 15) * 64, k0 = (w & 15) * 64;
    const float* W = (z == 0) ? Wq : (z == 1) ? Wk : (z == 2) ? Wv : Wo;
    u16* o = dstW + (size_t)z * Dm * Dm;

    {
        const int kr = tid >> 2, nc = (tid & 3) * 16;
        const float* s = W + (size_t)(k0 + kr) * Dm + n0 + nc;
        const float4* s4 = reinterpret_cast<const float4*>(s);
        float4 a = s4[0], b = s4[1], c = s4[2], d = s4[3];
        u32 t[8] = { pk_f16(a.x, a.y), pk_f16(a.z, a.w), pk_f16(b.x, b.y), pk_f16(b.z, b.w),
                     pk_f16(c.x, c.y), pk_f16(c.z, c.w), pk_f16(d.x, d.y), pk_f16(d.z, d.w) };
        *reinterpret_cast<uint4*>(&Ts[kr][nc])     = reinterpret_cast<uint4*>(t)[0];
        *reinterpret_cast<uint4*>(&Ts[kr][nc + 8]) = reinterpret_cast<uint4*>(t)[1];
    }
    __syncthreads();
    {
        const int nr = tid >> 2, kc = (tid & 3) * 16;
        u16 wv[16];
        #pragma unroll
        for (int j = 0; j < 16; ++j) wv[j] = Ts[kc + j][nr];
        u16* dptr = o + (size_t)(n0 + nr) * Dm + k0 + kc;
        *reinterpret_cast<uint4*>(dptr)     = reinterpret_cast<uint4*>(wv)[0];
        *reinterpret_cast<uint4*>(dptr + 8) = reinterpret_cast<uint4*>(wv)[1];
    }
}

// ---------------------------------------------------------------------------
// gemm_qkv (r7 form): 128x128 tile, BK=32, dbuf single-barrier K-loop, XCD
// remap. A (fp16 from prep) and B via DMA; drain before barriers. z==2
// stores V^T directly.
// ---------------------------------------------------------------------------
__global__ __launch_bounds__(256) void gemm_qkv(
    const u16* __restrict__ Abuf, const u16* __restrict__ Wtb,
    const float* __restrict__ bq, const float* __restrict__ bk, const float* __restrict__ bv,
    u16* __restrict__ Qh, u16* __restrict__ Kh, u16* __restrict__ Vth)
{
    __shared__ __align__(16) char smem[36864];   // main: As0/As1 @0/8192, Bs0/Bs1 @16384/24576; epi: 4x9216B

    const int tid = threadIdx.x;
    const int wave = tid >> 6, lane = tid & 63;
    const int quad = lane >> 4, l16 = lane & 15;
    const int wr = wave >> 1, wc = wave & 1;
    const int z = blockIdx.z;
    const u16* A  = Abuf + (size_t)z * M * Dm;
    const u16* Bt = Wtb  + (size_t)z * Dm * Dm;
    const float* bias = (z == 0) ? bq : (z == 1) ? bk : bv;
    u16* out = (z == 0) ? Qh : (z == 1) ? Kh : Vth;

    // XCD-locality remap (bijective on 256): m_idx in 0..31, n_idx in 0..7
    const int bid = blockIdx.y * 8 + blockIdx.x;
    const int m_idx = 4 * (bid & 7) + ((bid >> 3) & 3);
    const int n_idx = bid >> 5;
    const int n0 = n_idx * 128, m0 = m_idx * 128;

    const int srow = lane >> 2;
    const int skc  = (lane & 3) * 8;

    f32x4 acc[4][4] = {};

    auto stage = [&](int k0, int bi) {
        #pragma unroll
        for (int i = 0; i < 2; ++i) {
            const int ra = i * 64 + wave * 16;
            gl2lds16(A  + (size_t)(m0 + ra + srow) * Dm + k0 + skc, smem + bi * 8192 + ra * 64);
            gl2lds16(Bt + (size_t)(n0 + ra + srow) * Dm + k0 + skc, smem + 16384 + bi * 8192 + ra * 64);
        }
    };

    stage(0, 0);
    for (int k0 = 0, it = 0; k0 < Dm; k0 += 32, ++it) {
        const int cb = it & 1;
        drain_vm();        // tile-it DMAs (issued last iter) landed
        __syncthreads();
        if (k0 + 32 < Dm) stage(k0 + 32, cb ^ 1);
        const u16* Asb = (const u16*)(smem + cb * 8192);
        const u16* Bsb = (const u16*)(smem + 16384 + cb * 8192);
        f16x8 af[4], bf[4];
        #pragma unroll
        for (int t = 0; t < 4; ++t) {
            af[t] = *reinterpret_cast<const f16x8*>(&Asb[(wr * 64 + t * 16 + l16) * 32 + quad * 8]);
            bf[t] = *reinterpret_cast<const f16x8*>(&Bsb[(wc * 64 + t * 16 + l16) * 32 + quad * 8]);
        }
        #pragma unroll
        for (int mt = 0; mt < 4; ++mt)
            #pragma unroll
            for (int nt = 0; nt < 4; ++nt)
                acc[mt][nt] = __builtin_amdgcn_mfma_f32_16x16x32_f16(af[mt], bf[nt], acc[mt][nt], 0, 0, 0);
    }

    // ---- epilogue: C tile -> per-wave LDS [64][72] -> coalesced stores ----
    drain_vm();        // no DMA in flight when epilogue overlays smem
    __syncthreads();   // all main-loop LDS reads done before overlay
    u16* tile = (u16*)smem + wave * 4608;        // 64*72 u16 = 9216B per wave
    const float qscale = (z == 0) ? SC : 1.0f;
    #pragma unroll
    for (int nt = 0; nt < 4; ++nt) {
        const int n = n0 + wc * 64 + nt * 16 + l16;
        const float badd = bias[n];
        const int cc = nt * 16 + l16;
        #pragma unroll
        for (int mt = 0; mt < 4; ++mt) {
            #pragma unroll
            for (int r = 0; r < 4; ++r) {
                const int rr = mt * 16 + quad * 4 + r;
                const u16 vv = f2h((acc[mt][nt][r] + badd) * qscale);
                if (z == 2) tile[cc * 72 + rr] = vv;   // transposed: [d][ll]
                else        tile[rr * 72 + cc] = vv;   // [ll][d]
            }
        }
    }
    __syncthreads();

    const int rsub = lane >> 3;          // 0..7
    const int csub = (lane & 7) * 8;     // u16 col offset (16B)
    const int h2 = (n0 + wc * 64) >> 6;
    const int mb = m0 + wr * 64;
    const int bb = mb >> 11, ll0 = mb & 2047;
    if (z == 2) {
        const size_t baseV = ((size_t)(bb * H + h2)) * DH * L;
        #pragma unroll
        for (int j = 0; j < 8; ++j) {
            const int d = j * 8 + rsub;
            uint4 vv = *reinterpret_cast<const uint4*>(&tile[d * 72 + csub]);
            *reinterpret_cast<uint4*>(out + baseV + (size_t)d * L + ll0 + csub) = vv;
        }
    } else {
        const size_t base = ((size_t)(bb * H + h2)) * L * DH;
        #pragma unroll
        for (int j = 0; j < 8; ++j) {
            const int row = j * 8 + rsub;
            uint4 vv = *reinterpret_cast<const uint4*>(&tile[row * 72 + csub]);
            *reinterpret_cast<uint4*>(out + base + (size_t)(ll0 + row) * DH + csub) = vv;
        }
    }
}

// ---------------------------------------------------------------------------
// attn v12 (verified anchor): DMA-staged, (h,b)-major XCD map, explicit
// vmcnt(0) drains before every k-loop barrier.
// ---------------------------------------------------------------------------
__global__ __launch_bounds__(256) void attn(
    const u16* __restrict__ Qh, const u16* __restrict__ Kh,
    const u16* __restrict__ Vth, u16* __restrict__ Opart, float* __restrict__ rsums)
{
    __shared__ __align__(16) char smem[32768];   // 2 x (K 8KB + V 8KB); Os overlays buf0
    u16* Os = (u16*)smem;

    const int tid  = threadIdx.x;
    const int wave = tid >> 6, lane = tid & 63;
    const int l31  = lane & 31, hh = lane >> 5;

    // L2-locality decode: XCD = bid%8 = hb&7 (2MB K/V working set per XCD)
    const int bx  = blockIdx.x;
    const int hb  = (bx & 7) | ((bx >> 8) << 3);
    const int qth = (bx >> 3) & 31;
    const int h = hb & (H - 1), b = hb >> 4;
    const int qt = qth >> 1, half = qth & 1;

    const size_t hbase = ((size_t)(b * H + h)) * L * DH;
    const int q0 = qt * 128 + wave * 32;

    u16*  Op = Opart + (size_t)half * PER;
    float* rp = rsums + (size_t)half * NQ;

    // Q fragments (B operand), in regs
    f16x8 qf[4];
    {
        const u16* qp = Qh + hbase + (size_t)(q0 + l31) * DH + hh * 8;
        #pragma unroll
        for (int c = 0; c < 4; ++c)
            qf[c] = *reinterpret_cast<const f16x8*>(qp + c * 16);
    }

    // ones A-fragment for the row-sum MFMA (fp16 1.0 = 0x3C00)
    f16x8 ones;
    {
        u32 ov[4] = { 0x3C003C00u, 0x3C003C00u, 0x3C003C00u, 0x3C003C00u };
        ones = *reinterpret_cast<f16x8*>(ov);
    }

    const int r_off = lane >> 3;
    const int s_sl  = lane & 7;

    // DMA staging: pre-swizzled per-lane GLOBAL addresses, linear LDS dest.
    auto stage = [&](int kt, int bi) {
        char* base = smem + bi * 16384;
        #pragma unroll
        for (int i = 0; i < 2; ++i) {
            const int rr = wave * 16 + i * 8 + r_off;
            gl2lds16(Kh  + hbase + (size_t)(kt * 64 + rr) * DH + ((s_sl ^ (rr & 7)) << 3),
                     base + (wave * 16 + i * 8) * 128);
            gl2lds16(Vth + hbase + (size_t)rr * L + kt * 64 + ((s_sl ^ (rr & 7)) << 3),
                     base + 8192 + (wave * 16 + i * 8) * 128);
        }
    };

    int vbK[2], vbV[2];
    #pragma unroll
    for (int t = 0; t < 2; ++t) {
        const int rr = t * 32 + l31;
        vbK[t] = rr * 128 + ((rr & 7) << 4);
        vbV[t] = 8192 + rr * 128 + ((rr & 7) << 4);
    }

    f32x16 oacc[2] = {};
    f32x16 oaccR = {};   // row-sum accumulator (all 16 regs equal per lane)

    const int kt0 = half * 16;
    stage(kt0, 0);
    for (int ktl = 0; ktl < 16; ++ktl) {
        const int cb = ktl & 1;
        drain_vm();        // tile-ktl DMAs (issued last iter) landed
        __syncthreads();   // all waves' tile data visible; buf(cb^1) readers done
        if (ktl + 1 < 16) stage(kt0 + ktl + 1, cb ^ 1);
        const char* ldsb = smem + cb * 16384;

        // S^T = K @ Q^T
        f32x16 st[2] = {};
        #pragma unroll
        for (int t = 0; t < 2; ++t) {
            #pragma unroll
            for (int c = 0; c < 4; ++c) {
                f16x8 kf = *reinterpret_cast<const f16x8*>(ldsb + (vbK[t] ^ (((c << 1) | hh) << 4)));
                st[t] = __builtin_amdgcn_mfma_f32_32x32x16_f16(kf, qf[c], st[t], 0, 0, 0);
            }
        }

        // P = exp2(S^T); pack to fp16 words, then swap packed words across halves
        f16x8 pfrag[4];
        #pragma unroll
        for (int t = 0; t < 2; ++t) {
            float p[16];
            #pragma unroll
            for (int rr = 0; rr < 16; ++rr)
                p[rr] = __builtin_amdgcn_exp2f(st[t][rr]);
            #pragma unroll
            for (int g = 0; g < 2; ++g) {
                float* pg = p + g * 8;
                u32 w0 = pk_rtz(pg[0], pg[1]);
                u32 w1 = pk_rtz(pg[2], pg[3]);
                u32 w2 = pk_rtz(pg[4], pg[5]);
                u32 w3 = pk_rtz(pg[6], pg[7]);
                asm volatile("v_permlane32_swap_b32 %0, %1" : "+v"(w0), "+v"(w2));
                asm volatile("v_permlane32_swap_b32 %0, %1" : "+v"(w1), "+v"(w3));
                u32 pkv[4] = { w0, w1, w2, w3 };
                pfrag[t * 2 + g] = *reinterpret_cast<f16x8*>(pkv);
            }
        }

        // O^T += V^T @ P^T ; row-sums += ones @ P^T
        #pragma unroll
        for (int c = 0; c < 4; ++c) {
            #pragma unroll
            for (int t = 0; t < 2; ++t) {
                f16x8 vf = *reinterpret_cast<const f16x8*>(ldsb + (vbV[t] ^ (((c << 1) | hh) << 4)));
                oacc[t] = __builtin_amdgcn_mfma_f32_32x32x16_f16(vf, pfrag[c], oacc[t], 0, 0, 0);
            }
            oaccR = __builtin_amdgcn_mfma_f32_32x32x16_f16(ones, pfrag[c], oaccR, 0, 0, 0);
        }
    }

    // epilogue: unnormalized O^T -> LDS transpose -> coalesced partial store
    drain_vm();   // no DMA may be in flight when Os overlays buf0
    #pragma unroll
    for (int pass = 0; pass < 2; ++pass) {
        __syncthreads();
        if ((wave >> 1) == pass) {
            const int qloc = (wave & 1) * 32 + l31;
            #pragma unroll
            for (int t = 0; t < 2; ++t) {
                #pragma unroll
                for (int rq = 0; rq < 4; ++rq) {
                    const int d0 = t * 32 + rq * 8 + hh * 4;
                    *reinterpret_cast<u32*>(&Os[qloc * 72 + d0]) =
                        pk_f16(oacc[t][rq * 4 + 0], oacc[t][rq * 4 + 1]);
                    *reinterpret_cast<u32*>(&Os[qloc * 72 + d0 + 2]) =
                        pk_f16(oacc[t][rq * 4 + 2], oacc[t][rq * 4 + 3]);
                }
            }
        }
        __syncthreads();
        {
            const int row = tid >> 2, cc = (tid & 3) * 16;
            u16* dst = Op + hbase + (size_t)(qt * 128 + pass * 64 + row) * DH + cc;
            *reinterpret_cast<uint4*>(dst)     = *reinterpret_cast<const uint4*>(&Os[row * 72 + cc]);
            *reinterpret_cast<uint4*>(dst + 8) = *reinterpret_cast<const uint4*>(&Os[row * 72 + cc + 8]);
        }
    }
    if (hh == 0) rp[((size_t)(b * H + h)) * L + q0 + l31] = oaccR[0];
}

// ---------------------------------------------------------------------------
// attn_merge: ctx[b,l,h*64+d] = (O0+O1) / (r0+r1)
// ---------------------------------------------------------------------------
__global__ __launch_bounds__(256) void attn_merge(
    const u16* __restrict__ O0, const u16* __restrict__ O1,
    const float* __restrict__ r0, const float* __restrict__ r1,
    u16* __restrict__ ctx)
{
    const int g = blockIdx.x * 256 + threadIdx.x;
    const int row = g >> 3, dc = (g & 7) * 8;
    const int b = row >> 15, h = (row >> 11) & (H - 1), l = row & (L - 1);
    const float inv = 1.0f / (r0[row] + r1[row]);
    f16x8 a = *reinterpret_cast<const f16x8*>(O0 + (size_t)row * DH + dc);
    f16x8 c = *reinterpret_cast<const f16x8*>(O1 + (size_t)row * DH + dc);
    u32 o[4];
    #pragma unroll
    for (int i = 0; i < 4; ++i)
        o[i] = pk_f16(((float)a[2 * i] + (float)c[2 * i]) * inv,
                      ((float)a[2 * i + 1] + (float)c[2 * i + 1]) * inv);
    *reinterpret_cast<uint4*>(ctx + ((size_t)(b * L + l)) * Dm + h * DH + dc) =
        *reinterpret_cast<uint4*>(o);
}

// ---------------------------------------------------------------------------
// gemm_out (r12 form): out = ctx(fp16 [M][K]) @ Wot^T + bo -> fp32.
// 128x128 tile @ 512 threads (8 waves, 4m x 2n of 64x32 each), dbuf K-loop.
// ---------------------------------------------------------------------------
__global__ __launch_bounds__(512) void gemm_out(
    const u16* __restrict__ A, const u16* __restrict__ Bt,
    const float* __restrict__ bias, float* __restrict__ out)
{
    __shared__ u16 As[2][128 * 32];
    __shared__ u16 Bs[2][128 * 32];
    const int tid = threadIdx.x;
    const int wave = tid >> 6, lane = tid & 63;
    const int quad = lane >> 4, l16 = lane & 15;
    const int wr = wave >> 1, wc = wave & 1;   // wr 0..3 (32-row strip), wc 0..1 (64-col half)
    const int n0 = blockIdx.x * 128, m0 = blockIdx.y * 128;

    const int srow = lane >> 2;
    const int skc  = (lane & 3) * 8;

    f32x4 acc[2][4] = {};

    auto stage = [&](int k0, int bi) {
        gl2lds16(A  + (size_t)(m0 + wave * 16 + srow) * Dm + k0 + skc, &As[bi][(wave * 16) * 32]);
        gl2lds16(Bt + (size_t)(n0 + wave * 16 + srow) * Dm + k0 + skc, &Bs[bi][(wave * 16) * 32]);
    };

    stage(0, 0);
    for (int k0 = 0, it = 0; k0 < Dm; k0 += 32, ++it) {
        const int cb = it & 1;
        drain_vm();
        __syncthreads();
        if (k0 + 32 < Dm) stage(k0 + 32, cb ^ 1);
        f16x8 af[2], bf[4];
        #pragma unroll
        for (int t = 0; t < 2; ++t)
            af[t] = *reinterpret_cast<const f16x8*>(&As[cb][(wr * 32 + t * 16 + l16) * 32 + quad * 8]);
        #pragma unroll
        for (int t = 0; t < 4; ++t)
            bf[t] = *reinterpret_cast<const f16x8*>(&Bs[cb][(wc * 64 + t * 16 + l16) * 32 + quad * 8]);
        #pragma unroll
        for (int mt = 0; mt < 2; ++mt)
            #pragma unroll
            for (int nt = 0; nt < 4; ++nt)
                acc[mt][nt] = __builtin_amdgcn_mfma_f32_16x16x32_f16(af[mt], bf[nt], acc[mt][nt], 0, 0, 0);
    }

    #pragma unroll
    for (int nt = 0; nt < 4; ++nt) {
        const int n = n0 + wc * 64 + nt * 16 + l16;
        const float badd = bias[n];
        #pragma unroll
        for (int mt = 0; mt < 2; ++mt) {
            #pragma unroll
            for (int r = 0; r < 4; ++r) {
                const int m = m0 + wr * 32 + mt * 16 + quad * 4 + r;
                out[(size_t)m * Dm + n] = acc[mt][nt][r] + badd;
            }
        }
    }
}

// ---------------------------------------------------------------------------
extern "C" void kernel_launch(void* const* d_in, const int* in_sizes, int n_in,
                              void* d_out, int out_size, void* d_ws, size_t ws_size,
                              hipStream_t stream) {
    const float* q  = (const float*)d_in[0];
    const float* k  = (const float*)d_in[1];
    const float* v  = (const float*)d_in[2];
    const float* Wq = (const float*)d_in[3];
    const float* bq = (const float*)d_in[4];
    const float* Wk = (const float*)d_in[5];
    const float* bk = (const float*)d_in[6];
    const float* Wv = (const float*)d_in[7];
    const float* bv = (const float*)d_in[8];
    const float* Wo = (const float*)d_in[9];
    const float* bo = (const float*)d_in[10];
    float* out = (float*)d_out;

    // ws (u16 elems): Abuf 12M | Wt 4M | Qh 4M | Kh 4M | Vth 4M | O0 4M | O1 4M | rsums 2*64K f32
    u16* Abuf = (u16*)d_ws;
    u16* Wt   = Abuf + 3 * (size_t)M * Dm;
    u16* Qh   = Wt + 4 * (size_t)Dm * Dm;
    u16* Kh   = Qh + PER;
    u16* Vth  = Kh + PER;
    u16* O0   = Vth + PER;
    float* rs = (float*)(O0 + 2 * PER);
    u16* ctx  = Abuf;   // overlay (Abuf dead after gemm_qkv)

    prep       <<<3 * CIN_BLK + CWT_BLK, 256, 0, stream>>>(q, k, v, Wq, Wk, Wv, Wo, Abuf, Wt);
    gemm_qkv   <<<dim3(Dm / 128, M / 128, 3), 256, 0, stream>>>(Abuf, Wt, bq, bk, bv, Qh, Kh, Vth);
    attn       <<<dim3(L / 128 * 2 * H * Bn), 256, 0, stream>>>(Qh, Kh, Vth, O0, rs);
    attn_merge <<<NQ * 8 / 256, 256, 0, stream>>>(O0, O0 + PER, rs, rs + NQ, ctx);
    gemm_out   <<<dim3(Dm / 128, M / 128), 512, 0, stream>>>(ctx, Wt + 3 * (size_t)Dm * Dm, bo, out);
}

// Round 15
// 227.175 us; speedup vs baseline: 1.0243x; 1.0243x over previous
//
#include <hip/hip_runtime.h>
#include <cstdint>
#include <cstddef>

// fp16 internal pipeline. Verified absmax 9.77e-4 (r4-r14), race-stable with
// explicit vmcnt drains around DMA staging (r7+).
// r15: r12/r14 build + T5 s_setprio(1) around attn's QK and PV MFMA clusters.
// Precedent: m191 attn +4-7% (multi-block/CU, independently-phased regime =
// ours); null on lockstep GEMM (m190) so GEMMs untouched. Zero correctness
// risk (scheduler hint only; no sync/data change). Calibration from r12 vs
// r14 (identical source: 225.9 vs 232.7): total-level noise ~±7us; attn
// dispatch stable 52.5-54.2.
typedef _Float16 f16x8 __attribute__((ext_vector_type(8)));
typedef __fp16 fp16x2 __attribute__((ext_vector_type(2)));   // builtin cvt_pkrtz return type
typedef float f32x4 __attribute__((ext_vector_type(4)));
typedef float f32x16 __attribute__((ext_vector_type(16)));
typedef unsigned short u16;
typedef unsigned int u32;

static constexpr int Bn = 2;       // batch
static constexpr int L  = 2048;    // sequence
static constexpr int Dm = 1024;    // model dim
static constexpr int H  = 16;      // heads
static constexpr int DH = 64;      // head dim
static constexpr int M  = Bn * L;  // 4096 rows
static constexpr size_t PER = (size_t)Bn * H * L * DH;   // 4M elems
static constexpr int NQ = Bn * H * L;                    // 65536 q rows

static constexpr int CIN_BLK = (M * Dm) / 8 / 256;       // 2048 blocks per tensor
static constexpr int CWT_BLK = (Dm / 64) * (Dm / 64) * 4; // 1024 weight blocks

#define SC 0.18033688f   /* 0.125 * log2(e): folded into Q so QK^T is in exp2 domain */

// RNE fp32 -> fp16 (v_cvt_f16_f32, default round mode = RNE)
__device__ __forceinline__ u16 f2h(float f) {
    _Float16 h = (_Float16)f;
    u16 r; __builtin_memcpy(&r, &h, 2); return r;
}
// RNE pair -> packed u32
__device__ __forceinline__ u32 pk_f16(float a, float b) {
    return (u32)f2h(a) | ((u32)f2h(b) << 16);
}
// RTZ packed pair (single v_cvt_pk_f16_f32). Used ONLY for P, where the
// uniform downward bias cancels in the self-consistent row-sum normalization.
__device__ __forceinline__ u32 pk_rtz(float a, float b) {
#if __has_builtin(__builtin_amdgcn_cvt_pkrtz)
    fp16x2 t = __builtin_amdgcn_cvt_pkrtz(a, b);
    u32 r; __builtin_memcpy(&r, &t, 4); return r;
#else
    return pk_f16(a, b);
#endif
}

// async global->LDS, 16B per lane; LDS dest = wave-uniform base + lane*16
__device__ __forceinline__ void gl2lds16(const void* g, void* l) {
    __builtin_amdgcn_global_load_lds(
        (const __attribute__((address_space(1))) u32*)(uintptr_t)g,
        (__attribute__((address_space(3))) u32*)(uintptr_t)l, 16, 0, 0);
}

// explicit DMA drain before barriers (r7: closes the async-DMA hazard, costs ~0)
__device__ __forceinline__ void drain_vm() {
    asm volatile("s_waitcnt vmcnt(0)" ::: "memory");
}

// ---------------------------------------------------------------------------
// prep: merged convert_in + convert_wt (one dispatch, role by blockIdx.x).
//  - blocks [0, 3*CIN_BLK): fp32->fp16 flat copy of q,k,v
//  - blocks [3*CIN_BLK, +CWT_BLK): fp32 W [K][N] -> fp16 W^T [N][K]
// ---------------------------------------------------------------------------
__global__ __launch_bounds__(256) void prep(
    const float* __restrict__ q, const float* __restrict__ k, const float* __restrict__ v,
    const float* __restrict__ Wq, const float* __restrict__ Wk,
    const float* __restrict__ Wv, const float* __restrict__ Wo,
    u16* __restrict__ dstA, u16* __restrict__ dstW)
{
    __shared__ u16 Ts[64][72];
    const int wid = blockIdx.x;
    const int tid = threadIdx.x;

    if (wid < 3 * CIN_BLK) {
        const int y = wid >> 11;               // tensor select (CIN_BLK = 2048 = 1<<11)
        const float* src = (y == 0) ? q : (y == 1) ? k : v;
        u16* d = dstA + (size_t)y * M * Dm;
        const size_t t = (size_t)(wid & (CIN_BLK - 1)) * 256 + tid;
        const float4* s4 = reinterpret_cast<const float4*>(src) + t * 2;
        float4 f0 = s4[0], f1 = s4[1];
        u32 o[4] = { pk_f16(f0.x, f0.y), pk_f16(f0.z, f0.w),
                     pk_f16(f1.x, f1.y), pk_f16(f1.z, f1.w) };
        reinterpret_cast<uint4*>(d)[t] = *reinterpret_cast<uint4*>(o);
        return;
    }

    const int w = wid - 3 * CIN_BLK;           // 0..1023
    const int z = w >> 8;                      // weight select 0..3
    const int n0 = ((w >> 4) & 15) * 64, k0 = (w & 15) * 64;
    const float* W = (z == 0) ? Wq : (z == 1) ? Wk : (z == 2) ? Wv : Wo;
    u16* o = dstW + (size_t)z * Dm * Dm;

    {
        const int kr = tid >> 2, nc = (tid & 3) * 16;
        const float* s = W + (size_t)(k0 + kr) * Dm + n0 + nc;
        const float4* s4 = reinterpret_cast<const float4*>(s);
        float4 a = s4[0], b = s4[1], c = s4[2], d = s4[3];
        u32 t[8] = { pk_f16(a.x, a.y), pk_f16(a.z, a.w), pk_f16(b.x, b.y), pk_f16(b.z, b.w),
                     pk_f16(c.x, c.y), pk_f16(c.z, c.w), pk_f16(d.x, d.y), pk_f16(d.z, d.w) };
        *reinterpret_cast<uint4*>(&Ts[kr][nc])     = reinterpret_cast<uint4*>(t)[0];
        *reinterpret_cast<uint4*>(&Ts[kr][nc + 8]) = reinterpret_cast<uint4*>(t)[1];
    }
    __syncthreads();
    {
        const int nr = tid >> 2, kc = (tid & 3) * 16;
        u16 wv[16];
        #pragma unroll
        for (int j = 0; j < 16; ++j) wv[j] = Ts[kc + j][nr];
        u16* dptr = o + (size_t)(n0 + nr) * Dm + k0 + kc;
        *reinterpret_cast<uint4*>(dptr)     = reinterpret_cast<uint4*>(wv)[0];
        *reinterpret_cast<uint4*>(dptr + 8) = reinterpret_cast<uint4*>(wv)[1];
    }
}

// ---------------------------------------------------------------------------
// gemm_qkv (r7 form): 128x128 tile, BK=32, dbuf single-barrier K-loop, XCD
// remap. A (fp16 from prep) and B via DMA; drain before barriers. z==2
// stores V^T directly.
// ---------------------------------------------------------------------------
__global__ __launch_bounds__(256) void gemm_qkv(
    const u16* __restrict__ Abuf, const u16* __restrict__ Wtb,
    const float* __restrict__ bq, const float* __restrict__ bk, const float* __restrict__ bv,
    u16* __restrict__ Qh, u16* __restrict__ Kh, u16* __restrict__ Vth)
{
    __shared__ __align__(16) char smem[36864];   // main: As0/As1 @0/8192, Bs0/Bs1 @16384/24576; epi: 4x9216B

    const int tid = threadIdx.x;
    const int wave = tid >> 6, lane = tid & 63;
    const int quad = lane >> 4, l16 = lane & 15;
    const int wr = wave >> 1, wc = wave & 1;
    const int z = blockIdx.z;
    const u16* A  = Abuf + (size_t)z * M * Dm;
    const u16* Bt = Wtb  + (size_t)z * Dm * Dm;
    const float* bias = (z == 0) ? bq : (z == 1) ? bk : bv;
    u16* out = (z == 0) ? Qh : (z == 1) ? Kh : Vth;

    // XCD-locality remap (bijective on 256): m_idx in 0..31, n_idx in 0..7
    const int bid = blockIdx.y * 8 + blockIdx.x;
    const int m_idx = 4 * (bid & 7) + ((bid >> 3) & 3);
    const int n_idx = bid >> 5;
    const int n0 = n_idx * 128, m0 = m_idx * 128;

    const int srow = lane >> 2;
    const int skc  = (lane & 3) * 8;

    f32x4 acc[4][4] = {};

    auto stage = [&](int k0, int bi) {
        #pragma unroll
        for (int i = 0; i < 2; ++i) {
            const int ra = i * 64 + wave * 16;
            gl2lds16(A  + (size_t)(m0 + ra + srow) * Dm + k0 + skc, smem + bi * 8192 + ra * 64);
            gl2lds16(Bt + (size_t)(n0 + ra + srow) * Dm + k0 + skc, smem + 16384 + bi * 8192 + ra * 64);
        }
    };

    stage(0, 0);
    for (int k0 = 0, it = 0; k0 < Dm; k0 += 32, ++it) {
        const int cb = it & 1;
        drain_vm();        // tile-it DMAs (issued last iter) landed
        __syncthreads();
        if (k0 + 32 < Dm) stage(k0 + 32, cb ^ 1);
        const u16* Asb = (const u16*)(smem + cb * 8192);
        const u16* Bsb = (const u16*)(smem + 16384 + cb * 8192);
        f16x8 af[4], bf[4];
        #pragma unroll
        for (int t = 0; t < 4; ++t) {
            af[t] = *reinterpret_cast<const f16x8*>(&Asb[(wr * 64 + t * 16 + l16) * 32 + quad * 8]);
            bf[t] = *reinterpret_cast<const f16x8*>(&Bsb[(wc * 64 + t * 16 + l16) * 32 + quad * 8]);
        }
        #pragma unroll
        for (int mt = 0; mt < 4; ++mt)
            #pragma unroll
            for (int nt = 0; nt < 4; ++nt)
                acc[mt][nt] = __builtin_amdgcn_mfma_f32_16x16x32_f16(af[mt], bf[nt], acc[mt][nt], 0, 0, 0);
    }

    // ---- epilogue: C tile -> per-wave LDS [64][72] -> coalesced stores ----
    drain_vm();        // no DMA in flight when epilogue overlays smem
    __syncthreads();   // all main-loop LDS reads done before overlay
    u16* tile = (u16*)smem + wave * 4608;        // 64*72 u16 = 9216B per wave
    const float qscale = (z == 0) ? SC : 1.0f;
    #pragma unroll
    for (int nt = 0; nt < 4; ++nt) {
        const int n = n0 + wc * 64 + nt * 16 + l16;
        const float badd = bias[n];
        const int cc = nt * 16 + l16;
        #pragma unroll
        for (int mt = 0; mt < 4; ++mt) {
            #pragma unroll
            for (int r = 0; r < 4; ++r) {
                const int rr = mt * 16 + quad * 4 + r;
                const u16 vv = f2h((acc[mt][nt][r] + badd) * qscale);
                if (z == 2) tile[cc * 72 + rr] = vv;   // transposed: [d][ll]
                else        tile[rr * 72 + cc] = vv;   // [ll][d]
            }
        }
    }
    __syncthreads();

    const int rsub = lane >> 3;          // 0..7
    const int csub = (lane & 7) * 8;     // u16 col offset (16B)
    const int h2 = (n0 + wc * 64) >> 6;
    const int mb = m0 + wr * 64;
    const int bb = mb >> 11, ll0 = mb & 2047;
    if (z == 2) {
        const size_t baseV = ((size_t)(bb * H + h2)) * DH * L;
        #pragma unroll
        for (int j = 0; j < 8; ++j) {
            const int d = j * 8 + rsub;
            uint4 vv = *reinterpret_cast<const uint4*>(&tile[d * 72 + csub]);
            *reinterpret_cast<uint4*>(out + baseV + (size_t)d * L + ll0 + csub) = vv;
        }
    } else {
        const size_t base = ((size_t)(bb * H + h2)) * L * DH;
        #pragma unroll
        for (int j = 0; j < 8; ++j) {
            const int row = j * 8 + rsub;
            uint4 vv = *reinterpret_cast<const uint4*>(&tile[row * 72 + csub]);
            *reinterpret_cast<uint4*>(out + base + (size_t)(ll0 + row) * DH + csub) = vv;
        }
    }
}

// ---------------------------------------------------------------------------
// attn v13: v12 (verified anchor) + T5 setprio(1) around QK and PV MFMA
// clusters. DMA-staged, (h,b)-major XCD map, explicit vmcnt(0) drains.
// ---------------------------------------------------------------------------
__global__ __launch_bounds__(256) void attn(
    const u16* __restrict__ Qh, const u16* __restrict__ Kh,
    const u16* __restrict__ Vth, u16* __restrict__ Opart, float* __restrict__ rsums)
{
    __shared__ __align__(16) char smem[32768];   // 2 x (K 8KB + V 8KB); Os overlays buf0
    u16* Os = (u16*)smem;

    const int tid  = threadIdx.x;
    const int wave = tid >> 6, lane = tid & 63;
    const int l31  = lane & 31, hh = lane >> 5;

    // L2-locality decode: XCD = bid%8 = hb&7 (2MB K/V working set per XCD)
    const int bx  = blockIdx.x;
    const int hb  = (bx & 7) | ((bx >> 8) << 3);
    const int qth = (bx >> 3) & 31;
    const int h = hb & (H - 1), b = hb >> 4;
    const int qt = qth >> 1, half = qth & 1;

    const size_t hbase = ((size_t)(b * H + h)) * L * DH;
    const int q0 = qt * 128 + wave * 32;

    u16*  Op = Opart + (size_t)half * PER;
    float* rp = rsums + (size_t)half * NQ;

    // Q fragments (B operand), in regs
    f16x8 qf[4];
    {
        const u16* qp = Qh + hbase + (size_t)(q0 + l31) * DH + hh * 8;
        #pragma unroll
        for (int c = 0; c < 4; ++c)
            qf[c] = *reinterpret_cast<const f16x8*>(qp + c * 16);
    }

    // ones A-fragment for the row-sum MFMA (fp16 1.0 = 0x3C00)
    f16x8 ones;
    {
        u32 ov[4] = { 0x3C003C00u, 0x3C003C00u, 0x3C003C00u, 0x3C003C00u };
        ones = *reinterpret_cast<f16x8*>(ov);
    }

    const int r_off = lane >> 3;
    const int s_sl  = lane & 7;

    // DMA staging: pre-swizzled per-lane GLOBAL addresses, linear LDS dest.
    auto stage = [&](int kt, int bi) {
        char* base = smem + bi * 16384;
        #pragma unroll
        for (int i = 0; i < 2; ++i) {
            const int rr = wave * 16 + i * 8 + r_off;
            gl2lds16(Kh  + hbase + (size_t)(kt * 64 + rr) * DH + ((s_sl ^ (rr & 7)) << 3),
                     base + (wave * 16 + i * 8) * 128);
            gl2lds16(Vth + hbase + (size_t)rr * L + kt * 64 + ((s_sl ^ (rr & 7)) << 3),
                     base + 8192 + (wave * 16 + i * 8) * 128);
        }
    };

    int vbK[2], vbV[2];
    #pragma unroll
    for (int t = 0; t < 2; ++t) {
        const int rr = t * 32 + l31;
        vbK[t] = rr * 128 + ((rr & 7) << 4);
        vbV[t] = 8192 + rr * 128 + ((rr & 7) << 4);
    }

    f32x16 oacc[2] = {};
    f32x16 oaccR = {};   // row-sum accumulator (all 16 regs equal per lane)

    const int kt0 = half * 16;
    stage(kt0, 0);
    for (int ktl = 0; ktl < 16; ++ktl) {
        const int cb = ktl & 1;
        drain_vm();        // tile-ktl DMAs (issued last iter) landed
        __syncthreads();   // all waves' tile data visible; buf(cb^1) readers done
        if (ktl + 1 < 16) stage(kt0 + ktl + 1, cb ^ 1);
        const char* ldsb = smem + cb * 16384;

        // S^T = K @ Q^T  (T5: prio-1 so MFMA-phase waves preempt softmax waves)
        __builtin_amdgcn_s_setprio(1);
        f32x16 st[2] = {};
        #pragma unroll
        for (int t = 0; t < 2; ++t) {
            #pragma unroll
            for (int c = 0; c < 4; ++c) {
                f16x8 kf = *reinterpret_cast<const f16x8*>(ldsb + (vbK[t] ^ (((c << 1) | hh) << 4)));
                st[t] = __builtin_amdgcn_mfma_f32_32x32x16_f16(kf, qf[c], st[t], 0, 0, 0);
            }
        }
        __builtin_amdgcn_s_setprio(0);

        // P = exp2(S^T); pack to fp16 words, then swap packed words across halves
        f16x8 pfrag[4];
        #pragma unroll
        for (int t = 0; t < 2; ++t) {
            float p[16];
            #pragma unroll
            for (int rr = 0; rr < 16; ++rr)
                p[rr] = __builtin_amdgcn_exp2f(st[t][rr]);
            #pragma unroll
            for (int g = 0; g < 2; ++g) {
                float* pg = p + g * 8;
                u32 w0 = pk_rtz(pg[0], pg[1]);
                u32 w1 = pk_rtz(pg[2], pg[3]);
                u32 w2 = pk_rtz(pg[4], pg[5]);
                u32 w3 = pk_rtz(pg[6], pg[7]);
                asm volatile("v_permlane32_swap_b32 %0, %1" : "+v"(w0), "+v"(w2));
                asm volatile("v_permlane32_swap_b32 %0, %1" : "+v"(w1), "+v"(w3));
                u32 pkv[4] = { w0, w1, w2, w3 };
                pfrag[t * 2 + g] = *reinterpret_cast<f16x8*>(pkv);
            }
        }

        // O^T += V^T @ P^T ; row-sums += ones @ P^T  (T5: prio-1)
        __builtin_amdgcn_s_setprio(1);
        #pragma unroll
        for (int c = 0; c < 4; ++c) {
            #pragma unroll
            for (int t = 0; t < 2; ++t) {
                f16x8 vf = *reinterpret_cast<const f16x8*>(ldsb + (vbV[t] ^ (((c << 1) | hh) << 4)));
                oacc[t] = __builtin_amdgcn_mfma_f32_32x32x16_f16(vf, pfrag[c], oacc[t], 0, 0, 0);
            }
            oaccR = __builtin_amdgcn_mfma_f32_32x32x16_f16(ones, pfrag[c], oaccR, 0, 0, 0);
        }
        __builtin_amdgcn_s_setprio(0);
    }

    // epilogue: unnormalized O^T -> LDS transpose -> coalesced partial store
    drain_vm();   // no DMA may be in flight when Os overlays buf0
    #pragma unroll
    for (int pass = 0; pass < 2; ++pass) {
        __syncthreads();
        if ((wave >> 1) == pass) {
            const int qloc = (wave & 1) * 32 + l31;
            #pragma unroll
            for (int t = 0; t < 2; ++t) {
                #pragma unroll
                for (int rq = 0; rq < 4; ++rq) {
                    const int d0 = t * 32 + rq * 8 + hh * 4;
                    *reinterpret_cast<u32*>(&Os[qloc * 72 + d0]) =
                        pk_f16(oacc[t][rq * 4 + 0], oacc[t][rq * 4 + 1]);
                    *reinterpret_cast<u32*>(&Os[qloc * 72 + d0 + 2]) =
                        pk_f16(oacc[t][rq * 4 + 2], oacc[t][rq * 4 + 3]);
                }
            }
        }
        __syncthreads();
        {
            const int row = tid >> 2, cc = (tid & 3) * 16;
            u16* dst = Op + hbase + (size_t)(qt * 128 + pass * 64 + row) * DH + cc;
            *reinterpret_cast<uint4*>(dst)     = *reinterpret_cast<const uint4*>(&Os[row * 72 + cc]);
            *reinterpret_cast<uint4*>(dst + 8) = *reinterpret_cast<const uint4*>(&Os[row * 72 + cc + 8]);
        }
    }
    if (hh == 0) rp[((size_t)(b * H + h)) * L + q0 + l31] = oaccR[0];
}

// ---------------------------------------------------------------------------
// attn_merge: ctx[b,l,h*64+d] = (O0+O1) / (r0+r1)
// ---------------------------------------------------------------------------
__global__ __launch_bounds__(256) void attn_merge(
    const u16* __restrict__ O0, const u16* __restrict__ O1,
    const float* __restrict__ r0, const float* __restrict__ r1,
    u16* __restrict__ ctx)
{
    const int g = blockIdx.x * 256 + threadIdx.x;
    const int row = g >> 3, dc = (g & 7) * 8;
    const int b = row >> 15, h = (row >> 11) & (H - 1), l = row & (L - 1);
    const float inv = 1.0f / (r0[row] + r1[row]);
    f16x8 a = *reinterpret_cast<const f16x8*>(O0 + (size_t)row * DH + dc);
    f16x8 c = *reinterpret_cast<const f16x8*>(O1 + (size_t)row * DH + dc);
    u32 o[4];
    #pragma unroll
    for (int i = 0; i < 4; ++i)
        o[i] = pk_f16(((float)a[2 * i] + (float)c[2 * i]) * inv,
                      ((float)a[2 * i + 1] + (float)c[2 * i + 1]) * inv);
    *reinterpret_cast<uint4*>(ctx + ((size_t)(b * L + l)) * Dm + h * DH + dc) =
        *reinterpret_cast<uint4*>(o);
}

// ---------------------------------------------------------------------------
// gemm_out (r12 form): out = ctx(fp16 [M][K]) @ Wot^T + bo -> fp32.
// 128x128 tile @ 512 threads (8 waves, 4m x 2n of 64x32 each), dbuf K-loop.
// ---------------------------------------------------------------------------
__global__ __launch_bounds__(512) void gemm_out(
    const u16* __restrict__ A, const u16* __restrict__ Bt,
    const float* __restrict__ bias, float* __restrict__ out)
{
    __shared__ u16 As[2][128 * 32];
    __shared__ u16 Bs[2][128 * 32];
    const int tid = threadIdx.x;
    const int wave = tid >> 6, lane = tid & 63;
    const int quad = lane >> 4, l16 = lane & 15;
    const int wr = wave >> 1, wc = wave & 1;   // wr 0..3 (32-row strip), wc 0..1 (64-col half)
    const int n0 = blockIdx.x * 128, m0 = blockIdx.y * 128;

    const int srow = lane >> 2;
    const int skc  = (lane & 3) * 8;

    f32x4 acc[2][4] = {};

    auto stage = [&](int k0, int bi) {
        gl2lds16(A  + (size_t)(m0 + wave * 16 + srow) * Dm + k0 + skc, &As[bi][(wave * 16) * 32]);
        gl2lds16(Bt + (size_t)(n0 + wave * 16 + srow) * Dm + k0 + skc, &Bs[bi][(wave * 16) * 32]);
    };

    stage(0, 0);
    for (int k0 = 0, it = 0; k0 < Dm; k0 += 32, ++it) {
        const int cb = it & 1;
        drain_vm();
        __syncthreads();
        if (k0 + 32 < Dm) stage(k0 + 32, cb ^ 1);
        f16x8 af[2], bf[4];
        #pragma unroll
        for (int t = 0; t < 2; ++t)
            af[t] = *reinterpret_cast<const f16x8*>(&As[cb][(wr * 32 + t * 16 + l16) * 32 + quad * 8]);
        #pragma unroll
        for (int t = 0; t < 4; ++t)
            bf[t] = *reinterpret_cast<const f16x8*>(&Bs[cb][(wc * 64 + t * 16 + l16) * 32 + quad * 8]);
        #pragma unroll
        for (int mt = 0; mt < 2; ++mt)
            #pragma unroll
            for (int nt = 0; nt < 4; ++nt)
                acc[mt][nt] = __builtin_amdgcn_mfma_f32_16x16x32_f16(af[mt], bf[nt], acc[mt][nt], 0, 0, 0);
    }

    #pragma unroll
    for (int nt = 0; nt < 4; ++nt) {
        const int n = n0 + wc * 64 + nt * 16 + l16;
        const float badd = bias[n];
        #pragma unroll
        for (int mt = 0; mt < 2; ++mt) {
            #pragma unroll
            for (int r = 0; r < 4; ++r) {
                const int m = m0 + wr * 32 + mt * 16 + quad * 4 + r;
                out[(size_t)m * Dm + n] = acc[mt][nt][r] + badd;
            }
        }
    }
}

// ---------------------------------------------------------------------------
extern "C" void kernel_launch(void* const* d_in, const int* in_sizes, int n_in,
                              void* d_out, int out_size, void* d_ws, size_t ws_size,
                              hipStream_t stream) {
    const float* q  = (const float*)d_in[0];
    const float* k  = (const float*)d_in[1];
    const float* v  = (const float*)d_in[2];
    const float* Wq = (const float*)d_in[3];
    const float* bq = (const float*)d_in[4];
    const float* Wk = (const float*)d_in[5];
    const float* bk = (const float*)d_in[6];
    const float* Wv = (const float*)d_in[7];
    const float* bv = (const float*)d_in[8];
    const float* Wo = (const float*)d_in[9];
    const float* bo = (const float*)d_in[10];
    float* out = (float*)d_out;

    // ws (u16 elems): Abuf 12M | Wt 4M | Qh 4M | Kh 4M | Vth 4M | O0 4M | O1 4M | rsums 2*64K f32
    u16* Abuf = (u16*)d_ws;
    u16* Wt   = Abuf + 3 * (size_t)M * Dm;
    u16* Qh   = Wt + 4 * (size_t)Dm * Dm;
    u16* Kh   = Qh + PER;
    u16* Vth  = Kh + PER;
    u16* O0   = Vth + PER;
    float* rs = (float*)(O0 + 2 * PER);
    u16* ctx  = Abuf;   // overlay (Abuf dead after gemm_qkv)

    prep       <<<3 * CIN_BLK + CWT_BLK, 256, 0, stream>>>(q, k, v, Wq, Wk, Wv, Wo, Abuf, Wt);
    gemm_qkv   <<<dim3(Dm / 128, M / 128, 3), 256, 0, stream>>>(Abuf, Wt, bq, bk, bv, Qh, Kh, Vth);
    attn       <<<dim3(L / 128 * 2 * H * Bn), 256, 0, stream>>>(Qh, Kh, Vth, O0, rs);
    attn_merge <<<NQ * 8 / 256, 256, 0, stream>>>(O0, O0 + PER, rs, rs + NQ, ctx);
    gemm_out   <<<dim3(Dm / 128, M / 128), 512, 0, stream>>>(ctx, Wt + 3 * (size_t)Dm * Dm, bo, out);
}

// Round 16
// 225.920 us; speedup vs baseline: 1.0300x; 1.0056x over previous
//
#include <hip/hip_runtime.h>
#include <cstdint>
#include <cstddef>

// fp16 internal pipeline. Verified absmax 9.77e-4 (r4-r15), race-stable with
// explicit vmcnt drains around DMA staging (r7+).
// r16 (FINAL): revert to the r12/r14 session-best build. r15's T5 setprio
// regressed attn 53->58us via codegen perturbation (VGPR 88->104, VALUBusy
// 40->50%, MfmaUtil down) — the m191 precedent is a 1-wave-block structure;
// our 4-wave barrier-coupled block pays the cost without the benefit.
// Session ledger (verified): fp16 pipeline (accuracy fix), DMA staging +
// explicit drains (attn 90->53us + race fix), (h,b)-major XCD remap
// (FETCH 45->12MB), prep merge (+5.5us). Rejected by measurement: gemm_out
// fusion x3, 128x64 retile, write-late placement, T5. Remaining headroom
// (attn 33% MfmaUtil) gated on race-prone counted-vmcnt restructure.
typedef _Float16 f16x8 __attribute__((ext_vector_type(8)));
typedef __fp16 fp16x2 __attribute__((ext_vector_type(2)));   // builtin cvt_pkrtz return type
typedef float f32x4 __attribute__((ext_vector_type(4)));
typedef float f32x16 __attribute__((ext_vector_type(16)));
typedef unsigned short u16;
typedef unsigned int u32;

static constexpr int Bn = 2;       // batch
static constexpr int L  = 2048;    // sequence
static constexpr int Dm = 1024;    // model dim
static constexpr int H  = 16;      // heads
static constexpr int DH = 64;      // head dim
static constexpr int M  = Bn * L;  // 4096 rows
static constexpr size_t PER = (size_t)Bn * H * L * DH;   // 4M elems
static constexpr int NQ = Bn * H * L;                    // 65536 q rows

static constexpr int CIN_BLK = (M * Dm) / 8 / 256;       // 2048 blocks per tensor
static constexpr int CWT_BLK = (Dm / 64) * (Dm / 64) * 4; // 1024 weight blocks

#define SC 0.18033688f   /* 0.125 * log2(e): folded into Q so QK^T is in exp2 domain */

// RNE fp32 -> fp16 (v_cvt_f16_f32, default round mode = RNE)
__device__ __forceinline__ u16 f2h(float f) {
    _Float16 h = (_Float16)f;
    u16 r; __builtin_memcpy(&r, &h, 2); return r;
}
// RNE pair -> packed u32
__device__ __forceinline__ u32 pk_f16(float a, float b) {
    return (u32)f2h(a) | ((u32)f2h(b) << 16);
}
// RTZ packed pair (single v_cvt_pk_f16_f32). Used ONLY for P, where the
// uniform downward bias cancels in the self-consistent row-sum normalization.
__device__ __forceinline__ u32 pk_rtz(float a, float b) {
#if __has_builtin(__builtin_amdgcn_cvt_pkrtz)
    fp16x2 t = __builtin_amdgcn_cvt_pkrtz(a, b);
    u32 r; __builtin_memcpy(&r, &t, 4); return r;
#else
    return pk_f16(a, b);
#endif
}

// async global->LDS, 16B per lane; LDS dest = wave-uniform base + lane*16
__device__ __forceinline__ void gl2lds16(const void* g, void* l) {
    __builtin_amdgcn_global_load_lds(
        (const __attribute__((address_space(1))) u32*)(uintptr_t)g,
        (__attribute__((address_space(3))) u32*)(uintptr_t)l, 16, 0, 0);
}

// explicit DMA drain before barriers (r7: closes the async-DMA hazard, costs ~0)
__device__ __forceinline__ void drain_vm() {
    asm volatile("s_waitcnt vmcnt(0)" ::: "memory");
}

// ---------------------------------------------------------------------------
// prep: merged convert_in + convert_wt (one dispatch, role by blockIdx.x).
//  - blocks [0, 3*CIN_BLK): fp32->fp16 flat copy of q,k,v
//  - blocks [3*CIN_BLK, +CWT_BLK): fp32 W [K][N] -> fp16 W^T [N][K]
// ---------------------------------------------------------------------------
__global__ __launch_bounds__(256) void prep(
    const float* __restrict__ q, const float* __restrict__ k, const float* __restrict__ v,
    const float* __restrict__ Wq, const float* __restrict__ Wk,
    const float* __restrict__ Wv, const float* __restrict__ Wo,
    u16* __restrict__ dstA, u16* __restrict__ dstW)
{
    __shared__ u16 Ts[64][72];
    const int wid = blockIdx.x;
    const int tid = threadIdx.x;

    if (wid < 3 * CIN_BLK) {
        const int y = wid >> 11;               // tensor select (CIN_BLK = 2048 = 1<<11)
        const float* src = (y == 0) ? q : (y == 1) ? k : v;
        u16* d = dstA + (size_t)y * M * Dm;
        const size_t t = (size_t)(wid & (CIN_BLK - 1)) * 256 + tid;
        const float4* s4 = reinterpret_cast<const float4*>(src) + t * 2;
        float4 f0 = s4[0], f1 = s4[1];
        u32 o[4] = { pk_f16(f0.x, f0.y), pk_f16(f0.z, f0.w),
                     pk_f16(f1.x, f1.y), pk_f16(f1.z, f1.w) };
        reinterpret_cast<uint4*>(d)[t] = *reinterpret_cast<uint4*>(o);
        return;
    }

    const int w = wid - 3 * CIN_BLK;           // 0..1023
    const int z = w >> 8;                      // weight select 0..3
    const int n0 = ((w >> 4) & 15) * 64, k0 = (w & 15) * 64;
    const float* W = (z == 0) ? Wq : (z == 1) ? Wk : (z == 2) ? Wv : Wo;
    u16* o = dstW + (size_t)z * Dm * Dm;

    {
        const int kr = tid >> 2, nc = (tid & 3) * 16;
        const float* s = W + (size_t)(k0 + kr) * Dm + n0 + nc;
        const float4* s4 = reinterpret_cast<const float4*>(s);
        float4 a = s4[0], b = s4[1], c = s4[2], d = s4[3];
        u32 t[8] = { pk_f16(a.x, a.y), pk_f16(a.z, a.w), pk_f16(b.x, b.y), pk_f16(b.z, b.w),
                     pk_f16(c.x, c.y), pk_f16(c.z, c.w), pk_f16(d.x, d.y), pk_f16(d.z, d.w) };
        *reinterpret_cast<uint4*>(&Ts[kr][nc])     = reinterpret_cast<uint4*>(t)[0];
        *reinterpret_cast<uint4*>(&Ts[kr][nc + 8]) = reinterpret_cast<uint4*>(t)[1];
    }
    __syncthreads();
    {
        const int nr = tid >> 2, kc = (tid & 3) * 16;
        u16 wv[16];
        #pragma unroll
        for (int j = 0; j < 16; ++j) wv[j] = Ts[kc + j][nr];
        u16* dptr = o + (size_t)(n0 + nr) * Dm + k0 + kc;
        *reinterpret_cast<uint4*>(dptr)     = reinterpret_cast<uint4*>(wv)[0];
        *reinterpret_cast<uint4*>(dptr + 8) = reinterpret_cast<uint4*>(wv)[1];
    }
}

// ---------------------------------------------------------------------------
// gemm_qkv (r7 form): 128x128 tile, BK=32, dbuf single-barrier K-loop, XCD
// remap. A (fp16 from prep) and B via DMA; drain before barriers. z==2
// stores V^T directly.
// ---------------------------------------------------------------------------
__global__ __launch_bounds__(256) void gemm_qkv(
    const u16* __restrict__ Abuf, const u16* __restrict__ Wtb,
    const float* __restrict__ bq, const float* __restrict__ bk, const float* __restrict__ bv,
    u16* __restrict__ Qh, u16* __restrict__ Kh, u16* __restrict__ Vth)
{
    __shared__ __align__(16) char smem[36864];   // main: As0/As1 @0/8192, Bs0/Bs1 @16384/24576; epi: 4x9216B

    const int tid = threadIdx.x;
    const int wave = tid >> 6, lane = tid & 63;
    const int quad = lane >> 4, l16 = lane & 15;
    const int wr = wave >> 1, wc = wave & 1;
    const int z = blockIdx.z;
    const u16* A  = Abuf + (size_t)z * M * Dm;
    const u16* Bt = Wtb  + (size_t)z * Dm * Dm;
    const float* bias = (z == 0) ? bq : (z == 1) ? bk : bv;
    u16* out = (z == 0) ? Qh : (z == 1) ? Kh : Vth;

    // XCD-locality remap (bijective on 256): m_idx in 0..31, n_idx in 0..7
    const int bid = blockIdx.y * 8 + blockIdx.x;
    const int m_idx = 4 * (bid & 7) + ((bid >> 3) & 3);
    const int n_idx = bid >> 5;
    const int n0 = n_idx * 128, m0 = m_idx * 128;

    const int srow = lane >> 2;
    const int skc  = (lane & 3) * 8;

    f32x4 acc[4][4] = {};

    auto stage = [&](int k0, int bi) {
        #pragma unroll
        for (int i = 0; i < 2; ++i) {
            const int ra = i * 64 + wave * 16;
            gl2lds16(A  + (size_t)(m0 + ra + srow) * Dm + k0 + skc, smem + bi * 8192 + ra * 64);
            gl2lds16(Bt + (size_t)(n0 + ra + srow) * Dm + k0 + skc, smem + 16384 + bi * 8192 + ra * 64);
        }
    };

    stage(0, 0);
    for (int k0 = 0, it = 0; k0 < Dm; k0 += 32, ++it) {
        const int cb = it & 1;
        drain_vm();        // tile-it DMAs (issued last iter) landed
        __syncthreads();
        if (k0 + 32 < Dm) stage(k0 + 32, cb ^ 1);
        const u16* Asb = (const u16*)(smem + cb * 8192);
        const u16* Bsb = (const u16*)(smem + 16384 + cb * 8192);
        f16x8 af[4], bf[4];
        #pragma unroll
        for (int t = 0; t < 4; ++t) {
            af[t] = *reinterpret_cast<const f16x8*>(&Asb[(wr * 64 + t * 16 + l16) * 32 + quad * 8]);
            bf[t] = *reinterpret_cast<const f16x8*>(&Bsb[(wc * 64 + t * 16 + l16) * 32 + quad * 8]);
        }
        #pragma unroll
        for (int mt = 0; mt < 4; ++mt)
            #pragma unroll
            for (int nt = 0; nt < 4; ++nt)
                acc[mt][nt] = __builtin_amdgcn_mfma_f32_16x16x32_f16(af[mt], bf[nt], acc[mt][nt], 0, 0, 0);
    }

    // ---- epilogue: C tile -> per-wave LDS [64][72] -> coalesced stores ----
    drain_vm();        // no DMA in flight when epilogue overlays smem
    __syncthreads();   // all main-loop LDS reads done before overlay
    u16* tile = (u16*)smem + wave * 4608;        // 64*72 u16 = 9216B per wave
    const float qscale = (z == 0) ? SC : 1.0f;
    #pragma unroll
    for (int nt = 0; nt < 4; ++nt) {
        const int n = n0 + wc * 64 + nt * 16 + l16;
        const float badd = bias[n];
        const int cc = nt * 16 + l16;
        #pragma unroll
        for (int mt = 0; mt < 4; ++mt) {
            #pragma unroll
            for (int r = 0; r < 4; ++r) {
                const int rr = mt * 16 + quad * 4 + r;
                const u16 vv = f2h((acc[mt][nt][r] + badd) * qscale);
                if (z == 2) tile[cc * 72 + rr] = vv;   // transposed: [d][ll]
                else        tile[rr * 72 + cc] = vv;   // [ll][d]
            }
        }
    }
    __syncthreads();

    const int rsub = lane >> 3;          // 0..7
    const int csub = (lane & 7) * 8;     // u16 col offset (16B)
    const int h2 = (n0 + wc * 64) >> 6;
    const int mb = m0 + wr * 64;
    const int bb = mb >> 11, ll0 = mb & 2047;
    if (z == 2) {
        const size_t baseV = ((size_t)(bb * H + h2)) * DH * L;
        #pragma unroll
        for (int j = 0; j < 8; ++j) {
            const int d = j * 8 + rsub;
            uint4 vv = *reinterpret_cast<const uint4*>(&tile[d * 72 + csub]);
            *reinterpret_cast<uint4*>(out + baseV + (size_t)d * L + ll0 + csub) = vv;
        }
    } else {
        const size_t base = ((size_t)(bb * H + h2)) * L * DH;
        #pragma unroll
        for (int j = 0; j < 8; ++j) {
            const int row = j * 8 + rsub;
            uint4 vv = *reinterpret_cast<const uint4*>(&tile[row * 72 + csub]);
            *reinterpret_cast<uint4*>(out + base + (size_t)(ll0 + row) * DH + csub) = vv;
        }
    }
}

// ---------------------------------------------------------------------------
// attn v12 (verified anchor): DMA-staged, (h,b)-major XCD map, explicit
// vmcnt(0) drains before every k-loop barrier. No setprio (r15: -5us via
// codegen perturbation, VGPR 88->104).
// ---------------------------------------------------------------------------
__global__ __launch_bounds__(256) void attn(
    const u16* __restrict__ Qh, const u16* __restrict__ Kh,
    const u16* __restrict__ Vth, u16* __restrict__ Opart, float* __restrict__ rsums)
{
    __shared__ __align__(16) char smem[32768];   // 2 x (K 8KB + V 8KB); Os overlays buf0
    u16* Os = (u16*)smem;

    const int tid  = threadIdx.x;
    const int wave = tid >> 6, lane = tid & 63;
    const int l31  = lane & 31, hh = lane >> 5;

    // L2-locality decode: XCD = bid%8 = hb&7 (2MB K/V working set per XCD)
    const int bx  = blockIdx.x;
    const int hb  = (bx & 7) | ((bx >> 8) << 3);
    const int qth = (bx >> 3) & 31;
    const int h = hb & (H - 1), b = hb >> 4;
    const int qt = qth >> 1, half = qth & 1;

    const size_t hbase = ((size_t)(b * H + h)) * L * DH;
    const int q0 = qt * 128 + wave * 32;

    u16*  Op = Opart + (size_t)half * PER;
    float* rp = rsums + (size_t)half * NQ;

    // Q fragments (B operand), in regs
    f16x8 qf[4];
    {
        const u16* qp = Qh + hbase + (size_t)(q0 + l31) * DH + hh * 8;
        #pragma unroll
        for (int c = 0; c < 4; ++c)
            qf[c] = *reinterpret_cast<const f16x8*>(qp + c * 16);
    }

    // ones A-fragment for the row-sum MFMA (fp16 1.0 = 0x3C00)
    f16x8 ones;
    {
        u32 ov[4] = { 0x3C003C00u, 0x3C003C00u, 0x3C003C00u, 0x3C003C00u };
        ones = *reinterpret_cast<f16x8*>(ov);
    }

    const int r_off = lane >> 3;
    const int s_sl  = lane & 7;

    // DMA staging: pre-swizzled per-lane GLOBAL addresses, linear LDS dest.
    auto stage = [&](int kt, int bi) {
        char* base = smem + bi * 16384;
        #pragma unroll
        for (int i = 0; i < 2; ++i) {
            const int rr = wave * 16 + i * 8 + r_off;
            gl2lds16(Kh  + hbase + (size_t)(kt * 64 + rr) * DH + ((s_sl ^ (rr & 7)) << 3),
                     base + (wave * 16 + i * 8) * 128);
            gl2lds16(Vth + hbase + (size_t)rr * L + kt * 64 + ((s_sl ^ (rr & 7)) << 3),
                     base + 8192 + (wave * 16 + i * 8) * 128);
        }
    };

    int vbK[2], vbV[2];
    #pragma unroll
    for (int t = 0; t < 2; ++t) {
        const int rr = t * 32 + l31;
        vbK[t] = rr * 128 + ((rr & 7) << 4);
        vbV[t] = 8192 + rr * 128 + ((rr & 7) << 4);
    }

    f32x16 oacc[2] = {};
    f32x16 oaccR = {};   // row-sum accumulator (all 16 regs equal per lane)

    const int kt0 = half * 16;
    stage(kt0, 0);
    for (int ktl = 0; ktl < 16; ++ktl) {
        const int cb = ktl & 1;
        drain_vm();        // tile-ktl DMAs (issued last iter) landed
        __syncthreads();   // all waves' tile data visible; buf(cb^1) readers done
        if (ktl + 1 < 16) stage(kt0 + ktl + 1, cb ^ 1);
        const char* ldsb = smem + cb * 16384;

        // S^T = K @ Q^T
        f32x16 st[2] = {};
        #pragma unroll
        for (int t = 0; t < 2; ++t) {
            #pragma unroll
            for (int c = 0; c < 4; ++c) {
                f16x8 kf = *reinterpret_cast<const f16x8*>(ldsb + (vbK[t] ^ (((c << 1) | hh) << 4)));
                st[t] = __builtin_amdgcn_mfma_f32_32x32x16_f16(kf, qf[c], st[t], 0, 0, 0);
            }
        }

        // P = exp2(S^T); pack to fp16 words, then swap packed words across halves
        f16x8 pfrag[4];
        #pragma unroll
        for (int t = 0; t < 2; ++t) {
            float p[16];
            #pragma unroll
            for (int rr = 0; rr < 16; ++rr)
                p[rr] = __builtin_amdgcn_exp2f(st[t][rr]);
            #pragma unroll
            for (int g = 0; g < 2; ++g) {
                float* pg = p + g * 8;
                u32 w0 = pk_rtz(pg[0], pg[1]);
                u32 w1 = pk_rtz(pg[2], pg[3]);
                u32 w2 = pk_rtz(pg[4], pg[5]);
                u32 w3 = pk_rtz(pg[6], pg[7]);
                asm volatile("v_permlane32_swap_b32 %0, %1" : "+v"(w0), "+v"(w2));
                asm volatile("v_permlane32_swap_b32 %0, %1" : "+v"(w1), "+v"(w3));
                u32 pkv[4] = { w0, w1, w2, w3 };
                pfrag[t * 2 + g] = *reinterpret_cast<f16x8*>(pkv);
            }
        }

        // O^T += V^T @ P^T ; row-sums += ones @ P^T
        #pragma unroll
        for (int c = 0; c < 4; ++c) {
            #pragma unroll
            for (int t = 0; t < 2; ++t) {
                f16x8 vf = *reinterpret_cast<const f16x8*>(ldsb + (vbV[t] ^ (((c << 1) | hh) << 4)));
                oacc[t] = __builtin_amdgcn_mfma_f32_32x32x16_f16(vf, pfrag[c], oacc[t], 0, 0, 0);
            }
            oaccR = __builtin_amdgcn_mfma_f32_32x32x16_f16(ones, pfrag[c], oaccR, 0, 0, 0);
        }
    }

    // epilogue: unnormalized O^T -> LDS transpose -> coalesced partial store
    drain_vm();   // no DMA may be in flight when Os overlays buf0
    #pragma unroll
    for (int pass = 0; pass < 2; ++pass) {
        __syncthreads();
        if ((wave >> 1) == pass) {
            const int qloc = (wave & 1) * 32 + l31;
            #pragma unroll
            for (int t = 0; t < 2; ++t) {
                #pragma unroll
                for (int rq = 0; rq < 4; ++rq) {
                    const int d0 = t * 32 + rq * 8 + hh * 4;
                    *reinterpret_cast<u32*>(&Os[qloc * 72 + d0]) =
                        pk_f16(oacc[t][rq * 4 + 0], oacc[t][rq * 4 + 1]);
                    *reinterpret_cast<u32*>(&Os[qloc * 72 + d0 + 2]) =
                        pk_f16(oacc[t][rq * 4 + 2], oacc[t][rq * 4 + 3]);
                }
            }
        }
        __syncthreads();
        {
            const int row = tid >> 2, cc = (tid & 3) * 16;
            u16* dst = Op + hbase + (size_t)(qt * 128 + pass * 64 + row) * DH + cc;
            *reinterpret_cast<uint4*>(dst)     = *reinterpret_cast<const uint4*>(&Os[row * 72 + cc]);
            *reinterpret_cast<uint4*>(dst + 8) = *reinterpret_cast<const uint4*>(&Os[row * 72 + cc + 8]);
        }
    }
    if (hh == 0) rp[((size_t)(b * H + h)) * L + q0 + l31] = oaccR[0];
}

// ---------------------------------------------------------------------------
// attn_merge: ctx[b,l,h*64+d] = (O0+O1) / (r0+r1)
// ---------------------------------------------------------------------------
__global__ __launch_bounds__(256) void attn_merge(
    const u16* __restrict__ O0, const u16* __restrict__ O1,
    const float* __restrict__ r0, const float* __restrict__ r1,
    u16* __restrict__ ctx)
{
    const int g = blockIdx.x * 256 + threadIdx.x;
    const int row = g >> 3, dc = (g & 7) * 8;
    const int b = row >> 15, h = (row >> 11) & (H - 1), l = row & (L - 1);
    const float inv = 1.0f / (r0[row] + r1[row]);
    f16x8 a = *reinterpret_cast<const f16x8*>(O0 + (size_t)row * DH + dc);
    f16x8 c = *reinterpret_cast<const f16x8*>(O1 + (size_t)row * DH + dc);
    u32 o[4];
    #pragma unroll
    for (int i = 0; i < 4; ++i)
        o[i] = pk_f16(((float)a[2 * i] + (float)c[2 * i]) * inv,
                      ((float)a[2 * i + 1] + (float)c[2 * i + 1]) * inv);
    *reinterpret_cast<uint4*>(ctx + ((size_t)(b * L + l)) * Dm + h * DH + dc) =
        *reinterpret_cast<uint4*>(o);
}

// ---------------------------------------------------------------------------
// gemm_out (r12 form): out = ctx(fp16 [M][K]) @ Wot^T + bo -> fp32.
// 128x128 tile @ 512 threads (8 waves, 4m x 2n of 64x32 each), dbuf K-loop.
// ---------------------------------------------------------------------------
__global__ __launch_bounds__(512) void gemm_out(
    const u16* __restrict__ A, const u16* __restrict__ Bt,
    const float* __restrict__ bias, float* __restrict__ out)
{
    __shared__ u16 As[2][128 * 32];
    __shared__ u16 Bs[2][128 * 32];
    const int tid = threadIdx.x;
    const int wave = tid >> 6, lane = tid & 63;
    const int quad = lane >> 4, l16 = lane & 15;
    const int wr = wave >> 1, wc = wave & 1;   // wr 0..3 (32-row strip), wc 0..1 (64-col half)
    const int n0 = blockIdx.x * 128, m0 = blockIdx.y * 128;

    const int srow = lane >> 2;
    const int skc  = (lane & 3) * 8;

    f32x4 acc[2][4] = {};

    auto stage = [&](int k0, int bi) {
        gl2lds16(A  + (size_t)(m0 + wave * 16 + srow) * Dm + k0 + skc, &As[bi][(wave * 16) * 32]);
        gl2lds16(Bt + (size_t)(n0 + wave * 16 + srow) * Dm + k0 + skc, &Bs[bi][(wave * 16) * 32]);
    };

    stage(0, 0);
    for (int k0 = 0, it = 0; k0 < Dm; k0 += 32, ++it) {
        const int cb = it & 1;
        drain_vm();
        __syncthreads();
        if (k0 + 32 < Dm) stage(k0 + 32, cb ^ 1);
        f16x8 af[2], bf[4];
        #pragma unroll
        for (int t = 0; t < 2; ++t)
            af[t] = *reinterpret_cast<const f16x8*>(&As[cb][(wr * 32 + t * 16 + l16) * 32 + quad * 8]);
        #pragma unroll
        for (int t = 0; t < 4; ++t)
            bf[t] = *reinterpret_cast<const f16x8*>(&Bs[cb][(wc * 64 + t * 16 + l16) * 32 + quad * 8]);
        #pragma unroll
        for (int mt = 0; mt < 2; ++mt)
            #pragma unroll
            for (int nt = 0; nt < 4; ++nt)
                acc[mt][nt] = __builtin_amdgcn_mfma_f32_16x16x32_f16(af[mt], bf[nt], acc[mt][nt], 0, 0, 0);
    }

    #pragma unroll
    for (int nt = 0; nt < 4; ++nt) {
        const int n = n0 + wc * 64 + nt * 16 + l16;
        const float badd = bias[n];
        #pragma unroll
        for (int mt = 0; mt < 2; ++mt) {
            #pragma unroll
            for (int r = 0; r < 4; ++r) {
                const int m = m0 + wr * 32 + mt * 16 + quad * 4 + r;
                out[(size_t)m * Dm + n] = acc[mt][nt][r] + badd;
            }
        }
    }
}

// ---------------------------------------------------------------------------
extern "C" void kernel_launch(void* const* d_in, const int* in_sizes, int n_in,
                              void* d_out, int out_size, void* d_ws, size_t ws_size,
                              hipStream_t stream) {
    const float* q  = (const float*)d_in[0];
    const float* k  = (const float*)d_in[1];
    const float* v  = (const float*)d_in[2];
    const float* Wq = (const float*)d_in[3];
    const float* bq = (const float*)d_in[4];
    const float* Wk = (const float*)d_in[5];
    const float* bk = (const float*)d_in[6];
    const float* Wv = (const float*)d_in[7];
    const float* bv = (const float*)d_in[8];
    const float* Wo = (const float*)d_in[9];
    const float* bo = (const float*)d_in[10];
    float* out = (float*)d_out;

    // ws (u16 elems): Abuf 12M | Wt 4M | Qh 4M | Kh 4M | Vth 4M | O0 4M | O1 4M | rsums 2*64K f32
    u16* Abuf = (u16*)d_ws;
    u16* Wt   = Abuf + 3 * (size_t)M * Dm;
    u16* Qh   = Wt + 4 * (size_t)Dm * Dm;
    u16* Kh   = Qh + PER;
    u16* Vth  = Kh + PER;
    u16* O0   = Vth + PER;
    float* rs = (float*)(O0 + 2 * PER);
    u16* ctx  = Abuf;   // overlay (Abuf dead after gemm_qkv)

    prep       <<<3 * CIN_BLK + CWT_BLK, 256, 0, stream>>>(q, k, v, Wq, Wk, Wv, Wo, Abuf, Wt);
    gemm_qkv   <<<dim3(Dm / 128, M / 128, 3), 256, 0, stream>>>(Abuf, Wt, bq, bk, bv, Qh, Kh, Vth);
    attn       <<<dim3(L / 128 * 2 * H * Bn), 256, 0, stream>>>(Qh, Kh, Vth, O0, rs);
    attn_merge <<<NQ * 8 / 256, 256, 0, stream>>>(O0, O0 + PER, rs, rs + NQ, ctx);
    gemm_out   <<<dim3(Dm / 128, M / 128), 512, 0, stream>>>(ctx, Wt + 3 * (size_t)Dm * Dm, bo, out);
}